// Round 8
// baseline (167.797 us; speedup 1.0000x reference)
//
#include <hip/hip_runtime.h>
#include <math.h>

typedef _Float16 f16;
typedef __attribute__((ext_vector_type(2))) _Float16 f16x2;
typedef __attribute__((ext_vector_type(4))) _Float16 f16x4;
typedef __attribute__((ext_vector_type(8))) _Float16 f16x8;
typedef __attribute__((ext_vector_type(4))) float f32x4;

#define NBATCH 8
#define WSA_ELE 36864      // 32*1152 w_off, k-major, frag-swizzled
#define WSB_ELE 147456     // 128*1152 w_def, k-major, frag-swizzled
#define WPREP_BLOCKS 720   // (WSA_ELE + WSB_ELE) / 256
#define XPREP_BLOCKS 512   // transpose blocks
#define OPREP_BLOCKS 1024  // out bias-init blocks (4096 f32 each)
// workspace byte offsets
#define OFF_WSB  73728     // = WSA_ELE*2
#define OFF_XT   368640    // = OFF_WSB + WSB_ELE*2
#define OFF_OFFM 8757248   // = OFF_XT + 8*4096*128*2  (xt is 8 MB, NOT 4 MB!)

// ---- prep: weights->fp16 frag-swizzled + x NCHW->NHWC fp16 + out=bias ----
// swizzled element e = ((ch*NFRAG + mt)*64 + lane)*8 + j holds
// W[row = mt*16 + (lane&15)][kidx = ch*32 + (lane>>4)*8 + j], kidx = k*128 + cc.
__global__ __launch_bounds__(256) void prep_kernel(const float* __restrict__ x,
                                                   const float* __restrict__ w_off,
                                                   const float* __restrict__ w_def,
                                                   const float* __restrict__ b_def,
                                                   f16* __restrict__ wsA,
                                                   f16* __restrict__ wsB,
                                                   f16* __restrict__ xt,
                                                   float* __restrict__ out) {
  __shared__ f16 s_t[128 * 66];
  const int bid = blockIdx.x;
  const int t = threadIdx.x;
  if (bid < WPREP_BLOCKS) {
    int i = bid * 256 + t;
    if (i < WSA_ELE) {
      int j = i & 7, lane = (i >> 3) & 63, fm = i >> 9;
      int ch = fm >> 1, mt = fm & 1;
      int row = mt * 16 + (lane & 15);
      int kidx = ch * 32 + (lane >> 4) * 8 + j;
      int k = kidx >> 7, cc = kidx & 127;
      float v = (row < 27) ? w_off[row * 1152 + cc * 9 + k] : 0.0f;
      wsA[i] = (f16)v;
    } else {
      int e = i - WSA_ELE;
      int j = e & 7, lane = (e >> 3) & 63, fm = e >> 9;
      int ch = fm >> 3, mt = fm & 7;
      int row = mt * 16 + (lane & 15);
      int kidx = ch * 32 + (lane >> 4) * 8 + j;
      int k = kidx >> 7, cc = kidx & 127;
      wsB[e] = (f16)w_def[row * 1152 + cc * 9 + k];
    }
  } else if (bid < WPREP_BLOCKS + XPREP_BLOCKS) {
    const int bb = bid - WPREP_BLOCKS;
    const int b = bb >> 6;
    const int pos0 = (bb & 63) << 6;
    const float* xb = x + ((size_t)b << 19);
    for (int i = t; i < 8192; i += 256) {
      int c = i >> 6, p = i & 63;
      s_t[c * 66 + p] = (f16)xb[c * 4096 + pos0 + p];
    }
    __syncthreads();
    f16* xtb = xt + ((size_t)b << 19);
    for (int i = t; i < 4096; i += 256) {
      int p = i >> 6, c2 = (i & 63) * 2;
      unsigned v0 = *(const unsigned short*)&s_t[c2 * 66 + p];
      unsigned v1 = *(const unsigned short*)&s_t[(c2 + 1) * 66 + p];
      *(unsigned*)&xtb[(size_t)(pos0 + p) * 128 + c2] = v0 | (v1 << 16);
    }
  } else {
    const int ob = bid - (WPREP_BLOCKS + XPREP_BLOCKS);   // one 4096-f32 plane
    const float bv = b_def[ob & 127];
    float4 v = {bv, bv, bv, bv};
    float4* p = (float4*)(out + (size_t)ob * 4096 + t * 16);
    p[0] = v; p[1] = v; p[2] = v; p[3] = v;
  }
}

// ---- offset conv: barrier-free im2col MFMA (M=32, k-major K), writes offm ----
__global__ __launch_bounds__(256) void offset_conv_kernel(const f16* __restrict__ xt,
                                                          const f16* __restrict__ wsA,
                                                          const float* __restrict__ b_off,
                                                          float* __restrict__ offm) {
  const int t = threadIdx.x;
  const int b = blockIdx.x >> 6, ho = blockIdx.x & 63;
  const int lane = t & 63, wid = t >> 6;
  const int q = lane >> 4, li = lane & 15;
  const int px = (wid << 4) + li;
  const char* xtb = (const char*)xt + ((size_t)b << 20);

  f32x4 acc0 = {0.f, 0.f, 0.f, 0.f}, acc1 = {0.f, 0.f, 0.f, 0.f};

  for (int k = 0; k < 9; ++k) {
    const int ky = k / 3, kx = k - ky * 3;
    const int y = ho + ky - 1;
    const int xx = px + kx - 1;
    const bool valid = ((unsigned)y < 64u) && ((unsigned)xx < 64u);
    const int pos = min(max(y, 0), 63) * 64 + min(max(xx, 0), 63);
    const int voff = pos * 256 + q * 16;
    #pragma unroll
    for (int c4 = 0; c4 < 4; ++c4) {
      union { uint4 u; f16x8 v; } bu;
      bu.u = *(const uint4*)(xtb + voff + c4 * 64);
      if (!valid) { bu.u.x = 0u; bu.u.y = 0u; bu.u.z = 0u; bu.u.w = 0u; }
      const int ch = k * 4 + c4;
      f16x8 a0 = *(const f16x8*)&wsA[(ch * 2    ) * 512 + lane * 8];
      f16x8 a1 = *(const f16x8*)&wsA[(ch * 2 + 1) * 512 + lane * 8];
      acc0 = __builtin_amdgcn_mfma_f32_16x16x32_f16(a0, bu.v, acc0, 0, 0, 0);
      acc1 = __builtin_amdgcn_mfma_f32_16x16x32_f16(a1, bu.v, acc1, 0, 0, 0);
    }
  }

  float* om = offm + (size_t)b * 27 * 4096 + ho * 64 + px;
  #pragma unroll
  for (int mt = 0; mt < 2; ++mt) {
    f32x4 a = mt ? acc1 : acc0;
    #pragma unroll
    for (int r = 0; r < 4; ++r) {
      int oc = mt * 16 + q * 4 + r;
      if (oc < 27) {
        float v = a[r] + b_off[oc];
        if (oc >= 18) v = 1.0f / (1.0f + __expf(-v));
        om[oc * 4096] = v;
      }
    }
  }
}

// ---- DCNv2: barrier-free, A-frags direct from L1/L2, K-split 2, atomic out ----
// grid 1024: bid = half*512 + b*64 + ho. Half h covers K-chunks [h*18, h*18+18)
// (taps k in [h*4, h*4+4]). No __syncthreads in the main loop.
__global__ __launch_bounds__(256, 4) void dcn_kernel(const f16* __restrict__ xt,
                                                     const f16* __restrict__ wsB,
                                                     const float* __restrict__ offm,
                                                     float* __restrict__ out) {
  __shared__ ushort4 s_pos[5 * 64];   // 2560 B corner positions (this half's taps)
  __shared__ f16x4   s_wth[5 * 64];   // 2560 B modulated weights
  const int bid = blockIdx.x;
  const int half = bid >> 9;
  const int b = (bid >> 6) & 7, ho = bid & 63;
  const int t = threadIdx.x, lane = t & 63, wid = t >> 6;
  const int q = lane >> 4, li = lane & 15;
  const int px = (wid << 4) + li;
  const char* xtb = (const char*)xt + ((size_t)b << 20);
  const int klo = half * 4;

  // bilinear table for this half's 5 taps (once per block)
  const float* ob = offm + (size_t)b * 27 * 4096 + ho * 64;
  for (int f = t; f < 320; f += 256) {
    int kk = f >> 6, p = f & 63;
    int k = klo + kk;
    int ky = k / 3, kx = k - ky * 3;
    float oy = ob[(2 * k    ) * 4096 + p];
    float ox = ob[(2 * k + 1) * 4096 + p];
    float m  = ob[(18 + k   ) * 4096 + p];
    float py  = oy + (float)(ho + ky - 1);
    float pxf = ox + (float)(p + kx - 1);
    float y0f = floorf(py), x0f = floorf(pxf);
    float wy = py - y0f, wx = pxf - x0f;
    int y0 = (int)y0f, x0 = (int)x0f;
    int y1 = y0 + 1, x1 = x0 + 1;
    bool y0v = (unsigned)y0 < 64u, y1v = (unsigned)y1 < 64u;
    bool x0v = (unsigned)x0 < 64u, x1v = (unsigned)x1 < 64u;
    int y0c = min(max(y0, 0), 63), y1c = min(max(y1, 0), 63);
    int x0c = min(max(x0, 0), 63), x1c = min(max(x1, 0), 63);
    ushort4 p4;
    p4.x = (unsigned short)(y0c * 64 + x0c);
    p4.y = (unsigned short)(y0c * 64 + x1c);
    p4.z = (unsigned short)(y1c * 64 + x0c);
    p4.w = (unsigned short)(y1c * 64 + x1c);
    f16x4 wh;
    wh[0] = (f16)((y0v && x0v) ? (1.f - wy) * (1.f - wx) * m : 0.f);
    wh[1] = (f16)((y0v && x1v) ? (1.f - wy) * wx         * m : 0.f);
    wh[2] = (f16)((y1v && x0v) ? wy         * (1.f - wx) * m : 0.f);
    wh[3] = (f16)((y1v && x1v) ? wy         * wx         * m : 0.f);
    s_pos[f] = p4;
    s_wth[f] = wh;
  }
  __syncthreads();   // the only block barrier

  f32x4 acc[8];
  #pragma unroll
  for (int mt = 0; mt < 8; ++mt) acc[mt] = (f32x4){0.f, 0.f, 0.f, 0.f};

  const int cg0 = half * 18;
  #pragma unroll 6
  for (int s = 0; s < 18; ++s) {
    const int c4g = cg0 + s;
    const int k = c4g >> 2, c4 = c4g & 3;
    const int e = (k - klo) * 64 + px;
    const ushort4 p4 = s_pos[e];
    const f16x4   w4 = s_wth[e];
    const unsigned cb = (unsigned)(c4 * 64 + q * 16);
    union { uint4 u; f16x2 h[4]; } d0, d1, d2, d3;
    d0.u = *(const uint4*)(xtb + (((unsigned)p4.x << 8) + cb));
    d1.u = *(const uint4*)(xtb + (((unsigned)p4.y << 8) + cb));
    d2.u = *(const uint4*)(xtb + (((unsigned)p4.z << 8) + cb));
    d3.u = *(const uint4*)(xtb + (((unsigned)p4.w << 8) + cb));
    const f16x2 wp0 = {w4[0], w4[0]}, wp1 = {w4[1], w4[1]};
    const f16x2 wp2 = {w4[2], w4[2]}, wp3 = {w4[3], w4[3]};
    union { f16x2 h[4]; f16x8 v; } bf;
    #pragma unroll
    for (int i = 0; i < 4; ++i) {
      f16x2 sm = d0.h[i] * wp0;
      sm = sm + d1.h[i] * wp1;
      sm = sm + d2.h[i] * wp2;
      sm = sm + d3.h[i] * wp3;
      bf.h[i] = sm;
    }
    const f16* abase = wsB + (size_t)c4g * 4096;   // this chunk's 8 swizzled frags
    #pragma unroll
    for (int mt = 0; mt < 8; ++mt) {
      f16x8 a = *(const f16x8*)&abase[(mt * 64 + lane) * 8];
      acc[mt] = __builtin_amdgcn_mfma_f32_16x16x32_f16(a, bf.v, acc[mt], 0, 0, 0);
    }
  }

  // atomic accumulate into bias-pre-initialized out (2 addends per element)
  float* o = out + ((size_t)b << 19) + ho * 64 + px;
  #pragma unroll
  for (int mt = 0; mt < 8; ++mt) {
    #pragma unroll
    for (int r = 0; r < 4; ++r) {
      int oc = mt * 16 + q * 4 + r;
      atomicAdd(o + oc * 4096, acc[mt][r]);
    }
  }
}

extern "C" void kernel_launch(void* const* d_in, const int* in_sizes, int n_in,
                              void* d_out, int out_size, void* d_ws, size_t ws_size,
                              hipStream_t stream) {
  const float* x     = (const float*)d_in[0];
  const float* w_off = (const float*)d_in[1];
  const float* b_off = (const float*)d_in[2];
  const float* w_def = (const float*)d_in[3];
  const float* b_def = (const float*)d_in[4];
  float* out = (float*)d_out;

  f16*   wsA  = (f16*)d_ws;
  f16*   wsB  = (f16*)((char*)d_ws + OFF_WSB);
  f16*   xt   = (f16*)((char*)d_ws + OFF_XT);
  float* offm = (float*)((char*)d_ws + OFF_OFFM);

  prep_kernel<<<dim3(WPREP_BLOCKS + XPREP_BLOCKS + OPREP_BLOCKS), dim3(256), 0, stream>>>(
      x, w_off, w_def, b_def, wsA, wsB, xt, out);
  offset_conv_kernel<<<dim3(NBATCH * 64), dim3(256), 0, stream>>>(xt, wsA, b_off, offm);
  dcn_kernel<<<dim3(2 * NBATCH * 64), dim3(256), 0, stream>>>(xt, wsB, offm, out);
}

// Round 9
// 163.660 us; speedup vs baseline: 1.0253x; 1.0253x over previous
//
#include <hip/hip_runtime.h>
#include <math.h>

typedef _Float16 f16;
typedef __attribute__((ext_vector_type(2))) _Float16 f16x2;
typedef __attribute__((ext_vector_type(4))) _Float16 f16x4;
typedef __attribute__((ext_vector_type(8))) _Float16 f16x8;
typedef __attribute__((ext_vector_type(4))) float f32x4;

#define NBATCH 8
#define WSA_ELE 36864      // 32*1152 w_off, k-major, frag-swizzled
#define WSB_ELE 147456     // 128*1152 w_def, k-major, frag-swizzled
#define WPREP_BLOCKS 720   // (WSA_ELE + WSB_ELE) / 256
#define XPREP_BLOCKS 512   // transpose blocks
#define OPREP_BLOCKS 1024  // out bias-init blocks (4096 f32 each)
// workspace byte offsets
#define OFF_WSB  73728     // = WSA_ELE*2
#define OFF_XT   368640    // = OFF_WSB + WSB_ELE*2
#define OFF_OFFM 8757248   // = OFF_XT + 8*4096*128*2

// ---- prep: weights->fp16 frag-swizzled + x NCHW->NHWC fp16 + out=bias ----
__global__ __launch_bounds__(256) void prep_kernel(const float* __restrict__ x,
                                                   const float* __restrict__ w_off,
                                                   const float* __restrict__ w_def,
                                                   const float* __restrict__ b_def,
                                                   f16* __restrict__ wsA,
                                                   f16* __restrict__ wsB,
                                                   f16* __restrict__ xt,
                                                   float* __restrict__ out) {
  __shared__ f16 s_t[128 * 66];
  const int bid = blockIdx.x;
  const int t = threadIdx.x;
  if (bid < WPREP_BLOCKS) {
    int i = bid * 256 + t;
    if (i < WSA_ELE) {
      int j = i & 7, lane = (i >> 3) & 63, fm = i >> 9;
      int ch = fm >> 1, mt = fm & 1;
      int row = mt * 16 + (lane & 15);
      int kidx = ch * 32 + (lane >> 4) * 8 + j;
      int k = kidx >> 7, cc = kidx & 127;
      float v = (row < 27) ? w_off[row * 1152 + cc * 9 + k] : 0.0f;
      wsA[i] = (f16)v;
    } else {
      int e = i - WSA_ELE;
      int j = e & 7, lane = (e >> 3) & 63, fm = e >> 9;
      int ch = fm >> 3, mt = fm & 7;
      int row = mt * 16 + (lane & 15);
      int kidx = ch * 32 + (lane >> 4) * 8 + j;
      int k = kidx >> 7, cc = kidx & 127;
      wsB[e] = (f16)w_def[row * 1152 + cc * 9 + k];
    }
  } else if (bid < WPREP_BLOCKS + XPREP_BLOCKS) {
    const int bb = bid - WPREP_BLOCKS;
    const int b = bb >> 6;
    const int pos0 = (bb & 63) << 6;
    const float* xb = x + ((size_t)b << 19);
    for (int i = t; i < 8192; i += 256) {
      int c = i >> 6, p = i & 63;
      s_t[c * 66 + p] = (f16)xb[c * 4096 + pos0 + p];
    }
    __syncthreads();
    f16* xtb = xt + ((size_t)b << 19);
    for (int i = t; i < 4096; i += 256) {
      int p = i >> 6, c2 = (i & 63) * 2;
      unsigned v0 = *(const unsigned short*)&s_t[c2 * 66 + p];
      unsigned v1 = *(const unsigned short*)&s_t[(c2 + 1) * 66 + p];
      *(unsigned*)&xtb[(size_t)(pos0 + p) * 128 + c2] = v0 | (v1 << 16);
    }
  } else {
    const int ob = bid - (WPREP_BLOCKS + XPREP_BLOCKS);   // one 4096-f32 plane
    const float bv = b_def[ob & 127];
    float4 v = {bv, bv, bv, bv};
    float4* p = (float4*)(out + (size_t)ob * 4096 + t * 16);
    p[0] = v; p[1] = v; p[2] = v; p[3] = v;
  }
}

// ---- offset conv: barrier-free im2col MFMA, XCD-pinned batches ----
// grid 512: bid = ho*8 + b  (b = bid&7 -> all blocks of batch b on one XCD)
__global__ __launch_bounds__(256) void offset_conv_kernel(const f16* __restrict__ xt,
                                                          const f16* __restrict__ wsA,
                                                          const float* __restrict__ b_off,
                                                          float* __restrict__ offm) {
  const int t = threadIdx.x;
  const int b = blockIdx.x & 7, ho = blockIdx.x >> 3;
  const int lane = t & 63, wid = t >> 6;
  const int q = lane >> 4, li = lane & 15;
  const int px = (wid << 4) + li;
  const char* xtb = (const char*)xt + ((size_t)b << 20);

  f32x4 acc0 = {0.f, 0.f, 0.f, 0.f}, acc1 = {0.f, 0.f, 0.f, 0.f};

  for (int k = 0; k < 9; ++k) {
    const int ky = k / 3, kx = k - ky * 3;
    const int y = ho + ky - 1;
    const int xx = px + kx - 1;
    const bool valid = ((unsigned)y < 64u) && ((unsigned)xx < 64u);
    const int pos = min(max(y, 0), 63) * 64 + min(max(xx, 0), 63);
    const int voff = pos * 256 + q * 16;
    #pragma unroll
    for (int c4 = 0; c4 < 4; ++c4) {
      union { uint4 u; f16x8 v; } bu;
      bu.u = *(const uint4*)(xtb + voff + c4 * 64);
      if (!valid) { bu.u.x = 0u; bu.u.y = 0u; bu.u.z = 0u; bu.u.w = 0u; }
      const int ch = k * 4 + c4;
      f16x8 a0 = *(const f16x8*)&wsA[(ch * 2    ) * 512 + lane * 8];
      f16x8 a1 = *(const f16x8*)&wsA[(ch * 2 + 1) * 512 + lane * 8];
      acc0 = __builtin_amdgcn_mfma_f32_16x16x32_f16(a0, bu.v, acc0, 0, 0, 0);
      acc1 = __builtin_amdgcn_mfma_f32_16x16x32_f16(a1, bu.v, acc1, 0, 0, 0);
    }
  }

  float* om = offm + (size_t)b * 27 * 4096 + ho * 64 + px;
  #pragma unroll
  for (int mt = 0; mt < 2; ++mt) {
    f32x4 a = mt ? acc1 : acc0;
    #pragma unroll
    for (int r = 0; r < 4; ++r) {
      int oc = mt * 16 + q * 4 + r;
      if (oc < 27) {
        float v = a[r] + b_off[oc];
        if (oc >= 18) v = 1.0f / (1.0f + __expf(-v));
        om[oc * 4096] = v;
      }
    }
  }
}

// ---- DCNv2: barrier-free, XCD-pinned, 2-stage gather pipeline, K-split 2 ----
// grid 1024: bid = ((half*64 + ho) * 8) + b. Half h covers K-chunks [h*18,h*18+18)
// (taps k in [h*4, h*4+4]). b = bid&7 pins each batch to one XCD (round-robin
// dispatch) -> per-XCD L2 working set = 1 MB xt + 288 KB wsB + offm slice.
__global__ __launch_bounds__(256, 4) void dcn_kernel(const f16* __restrict__ xt,
                                                     const f16* __restrict__ wsB,
                                                     const float* __restrict__ offm,
                                                     float* __restrict__ out) {
  __shared__ ushort4 s_pos[5 * 64];   // corner positions (this half's 5 taps)
  __shared__ f16x4   s_wth[5 * 64];   // modulated bilinear weights
  const int bid = blockIdx.x;
  const int b = bid & 7;
  const int rest = bid >> 3;
  const int ho = rest & 63, half = rest >> 6;
  const int t = threadIdx.x, lane = t & 63, wid = t >> 6;
  const int q = lane >> 4, li = lane & 15;
  const int px = (wid << 4) + li;
  const char* xtb = (const char*)xt + ((size_t)b << 20);
  const int klo = half * 4;

  // bilinear table for this half's 5 taps (once per block)
  const float* ob = offm + (size_t)b * 27 * 4096 + ho * 64;
  for (int f = t; f < 320; f += 256) {
    int kk = f >> 6, p = f & 63;
    int k = klo + kk;
    int ky = k / 3, kx = k - ky * 3;
    float oy = ob[(2 * k    ) * 4096 + p];
    float ox = ob[(2 * k + 1) * 4096 + p];
    float m  = ob[(18 + k   ) * 4096 + p];
    float py  = oy + (float)(ho + ky - 1);
    float pxf = ox + (float)(p + kx - 1);
    float y0f = floorf(py), x0f = floorf(pxf);
    float wy = py - y0f, wx = pxf - x0f;
    int y0 = (int)y0f, x0 = (int)x0f;
    int y1 = y0 + 1, x1 = x0 + 1;
    bool y0v = (unsigned)y0 < 64u, y1v = (unsigned)y1 < 64u;
    bool x0v = (unsigned)x0 < 64u, x1v = (unsigned)x1 < 64u;
    int y0c = min(max(y0, 0), 63), y1c = min(max(y1, 0), 63);
    int x0c = min(max(x0, 0), 63), x1c = min(max(x1, 0), 63);
    ushort4 p4;
    p4.x = (unsigned short)(y0c * 64 + x0c);
    p4.y = (unsigned short)(y0c * 64 + x1c);
    p4.z = (unsigned short)(y1c * 64 + x0c);
    p4.w = (unsigned short)(y1c * 64 + x1c);
    f16x4 wh;
    wh[0] = (f16)((y0v && x0v) ? (1.f - wy) * (1.f - wx) * m : 0.f);
    wh[1] = (f16)((y0v && x1v) ? (1.f - wy) * wx         * m : 0.f);
    wh[2] = (f16)((y1v && x0v) ? wy         * (1.f - wx) * m : 0.f);
    wh[3] = (f16)((y1v && x1v) ? wy         * wx         * m : 0.f);
    s_pos[f] = p4;
    s_wth[f] = wh;
  }
  __syncthreads();   // the only block barrier

  f32x4 acc[8];
  #pragma unroll
  for (int mt = 0; mt < 8; ++mt) acc[mt] = (f32x4){0.f, 0.f, 0.f, 0.f};

  const int cg0 = half * 18;

  // 2-stage gather pipeline: prefetch step s+1's 4 corner loads during step s.
  uint4 dbuf[2][4];
  {
    const int c4g = cg0;
    const int k = c4g >> 2, c4 = c4g & 3;
    const ushort4 p4 = s_pos[(k - klo) * 64 + px];
    const unsigned cb = (unsigned)(c4 * 64 + q * 16);
    dbuf[0][0] = *(const uint4*)(xtb + (((unsigned)p4.x << 8) + cb));
    dbuf[0][1] = *(const uint4*)(xtb + (((unsigned)p4.y << 8) + cb));
    dbuf[0][2] = *(const uint4*)(xtb + (((unsigned)p4.z << 8) + cb));
    dbuf[0][3] = *(const uint4*)(xtb + (((unsigned)p4.w << 8) + cb));
  }
  #pragma unroll
  for (int s = 0; s < 18; ++s) {
    if (s < 17) {
      const int c4g = cg0 + s + 1;
      const int k = c4g >> 2, c4 = c4g & 3;
      const ushort4 p4 = s_pos[(k - klo) * 64 + px];
      const unsigned cb = (unsigned)(c4 * 64 + q * 16);
      uint4* dn = dbuf[(s + 1) & 1];
      dn[0] = *(const uint4*)(xtb + (((unsigned)p4.x << 8) + cb));
      dn[1] = *(const uint4*)(xtb + (((unsigned)p4.y << 8) + cb));
      dn[2] = *(const uint4*)(xtb + (((unsigned)p4.z << 8) + cb));
      dn[3] = *(const uint4*)(xtb + (((unsigned)p4.w << 8) + cb));
    }
    const int c4g = cg0 + s;
    const int k = c4g >> 2;
    const f16x4 w4 = s_wth[(k - klo) * 64 + px];
    const uint4* d = dbuf[s & 1];
    union { uint4 u; f16x2 h[4]; } u0, u1, u2, u3;
    u0.u = d[0]; u1.u = d[1]; u2.u = d[2]; u3.u = d[3];
    const f16x2 wp0 = {w4[0], w4[0]}, wp1 = {w4[1], w4[1]};
    const f16x2 wp2 = {w4[2], w4[2]}, wp3 = {w4[3], w4[3]};
    union { f16x2 h[4]; f16x8 v; } bf;
    #pragma unroll
    for (int i = 0; i < 4; ++i) {
      f16x2 sm = u0.h[i] * wp0;
      sm = sm + u1.h[i] * wp1;
      sm = sm + u2.h[i] * wp2;
      sm = sm + u3.h[i] * wp3;
      bf.h[i] = sm;
    }
    const f16* abase = wsB + (size_t)c4g * 4096;   // this chunk's 8 swizzled frags
    #pragma unroll
    for (int mt = 0; mt < 8; ++mt) {
      f16x8 a = *(const f16x8*)&abase[(mt * 64 + lane) * 8];
      acc[mt] = __builtin_amdgcn_mfma_f32_16x16x32_f16(a, bf.v, acc[mt], 0, 0, 0);
    }
  }

  // atomic accumulate into bias-pre-initialized out (2 addends per element)
  float* o = out + ((size_t)b << 19) + ho * 64 + px;
  #pragma unroll
  for (int mt = 0; mt < 8; ++mt) {
    #pragma unroll
    for (int r = 0; r < 4; ++r) {
      int oc = mt * 16 + q * 4 + r;
      atomicAdd(o + oc * 4096, acc[mt][r]);
    }
  }
}

extern "C" void kernel_launch(void* const* d_in, const int* in_sizes, int n_in,
                              void* d_out, int out_size, void* d_ws, size_t ws_size,
                              hipStream_t stream) {
  const float* x     = (const float*)d_in[0];
  const float* w_off = (const float*)d_in[1];
  const float* b_off = (const float*)d_in[2];
  const float* w_def = (const float*)d_in[3];
  const float* b_def = (const float*)d_in[4];
  float* out = (float*)d_out;

  f16*   wsA  = (f16*)d_ws;
  f16*   wsB  = (f16*)((char*)d_ws + OFF_WSB);
  f16*   xt   = (f16*)((char*)d_ws + OFF_XT);
  float* offm = (float*)((char*)d_ws + OFF_OFFM);

  prep_kernel<<<dim3(WPREP_BLOCKS + XPREP_BLOCKS + OPREP_BLOCKS), dim3(256), 0, stream>>>(
      x, w_off, w_def, b_def, wsA, wsB, xt, out);
  offset_conv_kernel<<<dim3(NBATCH * 64), dim3(256), 0, stream>>>(xt, wsA, b_off, offm);
  dcn_kernel<<<dim3(2 * NBATCH * 64), dim3(256), 0, stream>>>(xt, wsB, offm, out);
}